// Round 1
// baseline (1878.571 us; speedup 1.0000x reference)
//
#include <hip/hip_runtime.h>
#include <hip/hip_bf16.h>
#include <stdint.h>
#include <stddef.h>

// HeadLoraLinear: C = X @ W^T + 2.0 * (X @ A^T) @ B^T
//   X [2048,2048] f32, W [65536,2048] f32, A [64,2048] f32, B [65536,64] f32 -> C [2048,65536] f32
// LoRA folded into the main GEMM: X' = [bf16(X) | bf16(2*X@A^T)] (K'=2112) in ws.
// GEMM: 256x256 tile, BK=64, 8 waves (2Mx4N), phased schedule:
//   - LDS XOR-swizzle (slot ^= row&7): conflict-free ds_read_b128 + conflict-free B ds_writes (T2)
//   - A via global_load_lds w/ pre-swizzled GLOBAL source (linear LDS dest, rule 21)
//   - B reg-staged fp32 -> bf16 (hw v_cvt_pk via __bf16 cast, RNE) -> swizzled ds_write
//   - raw s_barrier phases, no per-K-step full drain; single vmcnt(0) per tile boundary,
//     waiting on loads issued one full tile (~3300 cyc) earlier (T3/T4-lite)
//   - s_setprio around each 16-MFMA cluster (T5), XCD-swizzled block id (T1)

#define IN_F   2048
#define OUT_F  65536
#define RANK   64
#define M_TOK  2048
#define KP     2112     // 2048 + 64
#define NT     33       // K' tiles of BK=64

#define BM 256
#define BN 256
#define BK 64
#define THREADS 512

typedef __attribute__((ext_vector_type(8))) short          short8;
typedef __attribute__((ext_vector_type(4))) float          float4v;
typedef __attribute__((ext_vector_type(4))) unsigned short ushort4v;
typedef __attribute__((ext_vector_type(8))) unsigned short ushort8v;

__device__ __forceinline__ unsigned short f2bf(float f) {   // manual RNE (kept for small kernels)
  union { float f; unsigned u; } v; v.f = f;
  return (unsigned short)((v.u + 0x7FFFu + ((v.u >> 16) & 1u)) >> 16);
}

__device__ __forceinline__ unsigned short f2bf_hw(float f) { // hw RNE: fptrunc -> v_cvt_pk_bf16_f32
  __bf16 h = (__bf16)f;
  return __builtin_bit_cast(unsigned short, h);
}

__device__ __forceinline__ void gload_lds16(const void* g, void* l) {
  __builtin_amdgcn_global_load_lds(
      (const __attribute__((address_space(1))) unsigned int*)g,
      (__attribute__((address_space(3))) unsigned int*)l, 16, 0, 0);
}

// ---- kernel 1: X fp32 -> bf16 into X' cols [0, 2048) ------------------------
__global__ void cvt_x_kernel(const float* __restrict__ x, unsigned short* __restrict__ xp) {
  const int row = blockIdx.x;
  const int c   = threadIdx.x * 8;
  const float4v* s = (const float4v*)(x + (size_t)row * IN_F + c);
  float4v a = s[0], b = s[1];
  ushort8v o;
  o[0] = f2bf(a.x); o[1] = f2bf(a.y); o[2] = f2bf(a.z); o[3] = f2bf(a.w);
  o[4] = f2bf(b.x); o[5] = f2bf(b.y); o[6] = f2bf(b.z); o[7] = f2bf(b.w);
  *(ushort8v*)(xp + (size_t)row * KP + c) = o;
}

// ---- kernel 2: low = 2 * X @ A^T -> bf16 into X' cols [2048, 2112) ----------
// One X-row per block (2048 blocks -> 8 blocks/CU, full occupancy). X-row staged
// once in LDS and read broadcast (wave-uniform); lane r streams A-row r from L2
// (A = 512 KB, stays hot across all blocks). Waves split K in quarters.
__global__ void low_kernel(const float* __restrict__ x, const float* __restrict__ A,
                           unsigned short* __restrict__ xp) {
  __shared__ float xrow[IN_F];       // 8 KB
  __shared__ float part[4][RANK];    // 1 KB
  const int row = blockIdx.x;
  const int t   = threadIdx.x;
  {
    const float4v* s = (const float4v*)(x + (size_t)row * IN_F);
    float4v a = s[t * 2], b = s[t * 2 + 1];
    *(float4v*)&xrow[t * 8]     = a;
    *(float4v*)&xrow[t * 8 + 4] = b;
  }
  __syncthreads();
  const int r = t & 63;          // lane -> A row (RANK=64)
  const int q = t >> 6;          // wave -> K quarter
  const float* ap = A + (size_t)r * IN_F + q * 512;
  const float* xq = xrow + q * 512;   // broadcast reads within wave (q wave-uniform)
  float acc = 0.f;
#pragma unroll 8
  for (int k = 0; k < 512; k += 4) {
    float4v a = *(const float4v*)(ap + k);
    acc += a.x * xq[k] + a.y * xq[k + 1] + a.z * xq[k + 2] + a.w * xq[k + 3];
  }
  part[q][r] = acc;
  __syncthreads();
  if (t < RANK) {
    float s = part[0][t] + part[1][t] + part[2][t] + part[3][t];
    xp[(size_t)row * KP + IN_F + t] = f2bf(2.0f * s);
  }
}

// ---- kernel 3: main GEMM, 256x256x64, 8 waves, phased schedule --------------
__global__ __launch_bounds__(THREADS, 2) void gemm_kernel(
    const unsigned short* __restrict__ xp, const float* __restrict__ W,
    const float* __restrict__ Bl, float* __restrict__ C) {
  __shared__ __align__(16) unsigned short As[2][BM * BK];   // 2 x 32 KB
  __shared__ __align__(16) unsigned short Bs[2][BN * BK];   // 2 x 32 KB  (128 KB total)

  const int t    = threadIdx.x;
  const int lane = t & 63;
  const int tm   = lane & 15;
  const int quad = lane >> 4;
  const int wid  = t >> 6;
  const int wr   = wid >> 2;     // 0..1 : m-half (rows wr*128 + [0,128))
  const int wc   = wid & 3;      // 0..3 : n-quarter (cols wc*64 + [0,64))

  // XCD-aware bijective swizzle (nwg=2048, %8==0). m-tile fastest within a
  // chunk so 8 consecutive blocks share one W n-slab (2 MB) in L2/L3.
  const int wg  = blockIdx.x;
  const int swz = (wg & 7) * (2048 / 8) + (wg >> 3);
  const int m0  = (swz & 7) * BM;
  const int n0  = (swz >> 3) * BN;

  // swizzled fragment offsets: LDS slot(row, s) holds data chunk s^(row&7);
  // row&7 == tm&7 for all fragment rows (tile bases are multiples of 16).
  const int s7   = tm & 7;
  const int sw0  = ((0 + quad) ^ s7) << 3;    // k-half 0: slot = quad
  const int sw1  = ((4 + quad) ^ s7) << 3;    // k-half 1: slot = 4+quad
  const int aOff = (wr * 128 + tm) * BK;
  const int bOff = (wc * 64 + tm) * BK;

  float4v acc[8][4] = {};
  float4v breg[8];

  // A tile (bf16): 4 x global_load_lds per thread; linear LDS dest, source
  // chunk pre-permuted so LDS holds the XOR-swizzled layout (m173 pattern).
  auto stageA = [&](int kt, int buf) {
#pragma unroll
    for (int i = 0; i < 4; ++i) {
      const int f = i * 512 + t;                // 16B-slot index, 0..2047
      const int row = f >> 3, sl = f & 7;
      const unsigned short* src =
          xp + (size_t)(m0 + row) * KP + kt * BK + ((sl ^ (row & 7)) << 3);
      gload_lds16(src, &As[buf][f * 8]);
    }
  };

  // B tile (fp32 in HBM): 8 x asm global_load_dwordx4 into regs (prefetch,
  // waited by the explicit vmcnt at the next boundary).
  auto loadB = [&](int kt) {
    const float* src; int rs, ko;
    if (kt < 32) { src = W;  rs = IN_F; ko = kt * BK; }
    else         { src = Bl; rs = RANK; ko = 0; }
#pragma unroll
    for (int j = 0; j < 8; ++j) {
      const int f = j * 512 + t;
      const int row = f >> 4, seg = f & 15;     // 16 lanes cover one row's 64 floats
      const float* p = src + (size_t)(n0 + row) * rs + ko + seg * 4;
      asm volatile("global_load_dwordx4 %0, %1, off" : "=v"(breg[j]) : "v"(p));
    }
  };

  // cvt fp32->bf16 (hw RNE) + swizzled ds_write_b64 (conflict-free by XOR spread)
  auto writeB = [&](int buf) {
#pragma unroll
    for (int j = 0; j < 8; ++j) {
      const int f = j * 512 + t;
      const int row = f >> 4, seg = f & 15;
      ushort4v o;
      o[0] = f2bf_hw(breg[j].x); o[1] = f2bf_hw(breg[j].y);
      o[2] = f2bf_hw(breg[j].z); o[3] = f2bf_hw(breg[j].w);
      const int eoff = row * BK + (((seg >> 1) ^ (row & 7)) << 3) + ((seg & 1) << 2);
      *(ushort4v*)&Bs[buf][eoff] = o;
    }
  };

  // ---- prologue: tile 0 resident, tile 1 in flight ----
  stageA(0, 0);
  loadB(0);
  asm volatile("s_waitcnt vmcnt(0)" ::: "memory");
  __builtin_amdgcn_sched_barrier(0);
  writeB(0);
  loadB(1);
  stageA(1, 1);
  asm volatile("s_waitcnt lgkmcnt(0)" ::: "memory");
  __builtin_amdgcn_sched_barrier(0);
  __builtin_amdgcn_s_barrier();

  for (int kt = 0; kt < NT; ++kt) {
    const int c = kt & 1;
    const unsigned short* ab = &As[c][0];
    const unsigned short* bb = &Bs[c][0];
    short8 a0[4][2], bfr[2][2];
#pragma unroll
    for (int p = 0; p < 4; ++p) {               // phases: (mh,nh) = 00,01,11,10
      const int mh = p >> 1;
      const int nh = (p == 1 || p == 2) ? 1 : 0;
      if (p == 0 || p == 2) {                   // fresh A half (8 x ds_read_b128)
#pragma unroll
        for (int ii = 0; ii < 4; ++ii) {
          const int ro = aOff + (mh * 4 + ii) * 16 * BK;
          a0[ii][0] = *(const short8*)&ab[ro + sw0];
          a0[ii][1] = *(const short8*)&ab[ro + sw1];
        }
      }
      if (p != 2) {                             // fresh B pair (4 x ds_read_b128)
#pragma unroll
        for (int jj = 0; jj < 2; ++jj) {
          const int ro = bOff + (nh * 2 + jj) * 16 * BK;
          bfr[jj][0] = *(const short8*)&bb[ro + sw0];
          bfr[jj][1] = *(const short8*)&bb[ro + sw1];
        }
      }
      __builtin_amdgcn_s_barrier();
      asm volatile("s_waitcnt lgkmcnt(0)" ::: "memory");
      __builtin_amdgcn_sched_barrier(0);
      __builtin_amdgcn_s_setprio(1);
#pragma unroll
      for (int ii = 0; ii < 4; ++ii)
#pragma unroll
        for (int jj = 0; jj < 2; ++jj) {
          acc[mh * 4 + ii][nh * 2 + jj] = __builtin_amdgcn_mfma_f32_16x16x32_bf16(
              a0[ii][0], bfr[jj][0], acc[mh * 4 + ii][nh * 2 + jj], 0, 0, 0);
          acc[mh * 4 + ii][nh * 2 + jj] = __builtin_amdgcn_mfma_f32_16x16x32_bf16(
              a0[ii][1], bfr[jj][1], acc[mh * 4 + ii][nh * 2 + jj], 0, 0, 0);
        }
      __builtin_amdgcn_s_setprio(0);
      __builtin_amdgcn_s_barrier();
      __builtin_amdgcn_sched_barrier(0);
    }

    if (kt == NT - 1) break;
    // ---- tile boundary: after p3's barrier all waves are done reading buf c.
    // vmcnt(0) drains loads issued a full tile (~3300 cyc) ago -> near-zero stall;
    // tile kt+2's loads issue right after and stay in flight across tile kt+1.
    asm volatile("s_waitcnt vmcnt(0)" ::: "memory");
    __builtin_amdgcn_sched_barrier(0);
    writeB(c ^ 1);                               // B(kt+1) regs -> buf c^1
    if (kt + 2 < NT) {
      loadB(kt + 2);                             // fp32 -> regs (next boundary)
      stageA(kt + 2, c);                         // bf16 -> freed buf c
    }
    asm volatile("s_waitcnt lgkmcnt(0)" ::: "memory");
    __builtin_amdgcn_sched_barrier(0);
    __builtin_amdgcn_s_barrier();
  }

  // ---- epilogue: C/D layout col = lane&15, row = quad*4 + reg (m89-verified) ----
#pragma unroll
  for (int i = 0; i < 8; ++i) {
    const int mrow = m0 + wr * 128 + i * 16 + quad * 4;
#pragma unroll
    for (int j = 0; j < 4; ++j) {
      const int ncol = n0 + wc * 64 + j * 16 + tm;
      float4v v = acc[i][j];
      C[(size_t)(mrow + 0) * OUT_F + ncol] = v.x;
      C[(size_t)(mrow + 1) * OUT_F + ncol] = v.y;
      C[(size_t)(mrow + 2) * OUT_F + ncol] = v.z;
      C[(size_t)(mrow + 3) * OUT_F + ncol] = v.w;
    }
  }
}

extern "C" void kernel_launch(void* const* d_in, const int* in_sizes, int n_in,
                              void* d_out, int out_size, void* d_ws, size_t ws_size,
                              hipStream_t stream) {
  const float* x  = (const float*)d_in[0];
  const float* W  = (const float*)d_in[1];
  const float* lA = (const float*)d_in[2];
  const float* lB = (const float*)d_in[3];
  float* out = (float*)d_out;
  unsigned short* xp = (unsigned short*)d_ws;  // X' [2048, 2112] bf16 = 8.65 MB

  hipLaunchKernelGGL(cvt_x_kernel, dim3(M_TOK), dim3(256), 0, stream, x, xp);
  hipLaunchKernelGGL(low_kernel, dim3(M_TOK), dim3(256), 0, stream, x, lA, xp);
  hipLaunchKernelGGL(gemm_kernel, dim3(2048), dim3(THREADS), 0, stream,
                     xp, W, lB, out);
}